// Round 1
// baseline (173.116 us; speedup 1.0000x reference)
//
#include <hip/hip_runtime.h>
#include <math.h>

#define BB 32
#define CC 2048
#define NN 784          // 28*28
#define MM 4
#define NCHUNK 8
#define CPERCH (CC / NCHUNK)   // 256
#define LAMBDA_ 1e-3f
#define EPS_ 1e-10f
#define LOG1E4 9.210340371976184f

__device__ __forceinline__ float wred(float v) {
#pragma unroll
  for (int off = 32; off > 0; off >>= 1) v += __shfl_down(v, off, 64);
  return v;
}

// ---- pass 1: inv_norm[b*C+c] = 1/max(||x[b,c,:]||, eps) ----
__global__ __launch_bounds__(256) void k_norm(const float* __restrict__ x,
                                              float* __restrict__ inv_norm) {
  int idx  = blockIdx.x * 4 + (threadIdx.x >> 6);   // (b*C+c)
  int lane = threadIdx.x & 63;
  const float* row = x + (size_t)idx * NN;
  float ss = 0.f;
  for (int n = lane; n < NN; n += 64) { float v = row[n]; ss += v * v; }
  ss = wred(ss);
  if (lane == 0) inv_norm[idx] = 1.0f / fmaxf(sqrtf(ss), EPS_);
}

// ---- peW[m*N+n] = sum_c pe[n,c] * W[m,c]  (batch-independent) ----
__global__ __launch_bounds__(256) void k_peW(const float* __restrict__ W,
                                             float* __restrict__ peW) {
  int n    = blockIdx.x;
  int m    = threadIdx.x >> 6;
  int lane = threadIdx.x & 63;
  float acc = 0.f;
  for (int c = lane; c < CC; c += 64) {
    float fc  = (float)(c & ~1);
    float di  = expf(-(fc / (float)CC) * LOG1E4);
    float arg = (float)n * di;
    float pe  = (c & 1) ? cosf(arg) : sinf(arg);
    acc += pe * W[m * CC + c];
  }
  acc = wred(acc);
  if (lane == 0) peW[m * NN + n] = acc;
}

// ---- pass 2: partial sums of s[b,m,n] over c-chunks (deterministic) ----
__global__ __launch_bounds__(256) void k_sacc(const float* __restrict__ x,
                                              const float* __restrict__ W,
                                              const float* __restrict__ inv_norm,
                                              float* __restrict__ sPart) {
  int n  = blockIdx.x * 256 + threadIdx.x;
  int ch = blockIdx.y;
  int b  = blockIdx.z;
  bool valid = n < NN;
  float a0 = 0.f, a1 = 0.f, a2 = 0.f, a3 = 0.f;
  const float* xb   = x + (size_t)b * CC * NN;
  const float* invb = inv_norm + b * CC;
  int c0 = ch * CPERCH;
#pragma unroll 4
  for (int i = 0; i < CPERCH; ++i) {
    int c = c0 + i;
    float xv = valid ? xb[(size_t)c * NN + n] : 0.f;
    float xw = xv * invb[c];
    a0 += xw * W[0 * CC + c];
    a1 += xw * W[1 * CC + c];
    a2 += xw * W[2 * CC + c];
    a3 += xw * W[3 * CC + c];
  }
  if (valid) {
    size_t base = (((size_t)b * NCHUNK + ch) * MM) * NN + n;
    sPart[base + 0 * NN] = a0;
    sPart[base + 1 * NN] = a1;
    sPart[base + 2 * NN] = a2;
    sPart[base + 3 * NN] = a3;
  }
}

// ---- hid4[(b*N+n)*4 + m] = sigmoid(peW[m,n] + sum_ch sPart) ----
__global__ __launch_bounds__(256) void k_hid(const float* __restrict__ sPart,
                                             const float* __restrict__ peW,
                                             float* __restrict__ hid4) {
  int n = blockIdx.x * 256 + threadIdx.x;
  int b = blockIdx.y;
  if (n >= NN) return;
  float h[MM];
#pragma unroll
  for (int m = 0; m < MM; ++m) {
    float s = peW[m * NN + n];
#pragma unroll
    for (int ch = 0; ch < NCHUNK; ++ch)
      s += sPart[(((size_t)b * NCHUNK + ch) * MM + m) * NN + n];
    h[m] = 1.f / (1.f + expf(-s));
  }
  float4 hv = make_float4(h[0], h[1], h[2], h[3]);
  *(float4*)(hid4 + ((size_t)b * NN + n) * 4) = hv;
}

// ---- invden[b*M+m] = 1/(sum_n hid^2 + lambda) ----
__global__ __launch_bounds__(64) void k_den(const float* __restrict__ hid4,
                                            float* __restrict__ invden) {
  int idx = blockIdx.x;           // b*M+m
  int b = idx >> 2, m = idx & 3;
  int lane = threadIdx.x;
  float acc = 0.f;
  for (int n = lane; n < NN; n += 64) {
    float h = hid4[((size_t)b * NN + n) * 4 + m];
    acc += h * h;
  }
  acc = wred(acc);
  if (lane == 0) invden[idx] = 1.f / (acc + LAMBDA_);
}

// ---- pass 3: out[b,c] = sum_m invden*(inv_norm*sum_n x*hid + sum_n pe*hid) ----
__global__ __launch_bounds__(256) void k_out(const float* __restrict__ x,
                                             const float* __restrict__ hid4,
                                             const float* __restrict__ inv_norm,
                                             const float* __restrict__ invden,
                                             float* __restrict__ out) {
  int idx  = blockIdx.x * 4 + (threadIdx.x >> 6);   // (b*C+c)
  int lane = threadIdx.x & 63;
  int b = idx >> 11;            // /C  (C=2048)
  int c = idx & (CC - 1);
  const float* row = x + (size_t)idx * NN;
  const float4* hb = (const float4*)(hid4 + (size_t)b * NN * 4);
  float di = expf(-((float)(c & ~1) / (float)CC) * LOG1E4);
  bool use_sin = !(c & 1);
  float aX0=0,aX1=0,aX2=0,aX3=0, aP0=0,aP1=0,aP2=0,aP3=0;
  for (int n = lane; n < NN; n += 64) {
    float xv = row[n];
    float4 h = hb[n];
    float arg = (float)n * di;
    float pe  = use_sin ? sinf(arg) : cosf(arg);
    aX0 += xv * h.x; aX1 += xv * h.y; aX2 += xv * h.z; aX3 += xv * h.w;
    aP0 += pe * h.x; aP1 += pe * h.y; aP2 += pe * h.z; aP3 += pe * h.w;
  }
  aX0 = wred(aX0); aX1 = wred(aX1); aX2 = wred(aX2); aX3 = wred(aX3);
  aP0 = wred(aP0); aP1 = wred(aP1); aP2 = wred(aP2); aP3 = wred(aP3);
  if (lane == 0) {
    float inv = inv_norm[idx];
    const float* dv = invden + b * MM;
    float r = dv[0] * (inv * aX0 + aP0)
            + dv[1] * (inv * aX1 + aP1)
            + dv[2] * (inv * aX2 + aP2)
            + dv[3] * (inv * aX3 + aP3);
    if (isnan(r)) r = 0.f;
    else if (isinf(r)) r = (r > 0.f) ? 3.4028234663852886e38f : -3.4028234663852886e38f;
    out[idx] = r;
  }
}

extern "C" void kernel_launch(void* const* d_in, const int* in_sizes, int n_in,
                              void* d_out, int out_size, void* d_ws, size_t ws_size,
                              hipStream_t stream) {
  const float* x = (const float*)d_in[0];   // (B, C, S, S)
  const float* W = (const float*)d_in[1];   // (M, C, 1)
  float* out = (float*)d_out;               // (B, 1, C)
  float* ws  = (float*)d_ws;

  float* inv_norm = ws;                                      // B*C       = 65536
  float* peW      = inv_norm + (size_t)BB * CC;              // M*N       = 3136
  float* sPart    = peW + (size_t)MM * NN;                   // B*8*M*N   = 802816
  float* hid4     = sPart + (size_t)BB * NCHUNK * MM * NN;   // B*N*M     = 401408
  float* invden   = hid4 + (size_t)BB * NN * MM;             // B*M       = 128

  k_norm<<<BB * CC / 4, 256, 0, stream>>>(x, inv_norm);
  k_peW <<<NN, 256, 0, stream>>>(W, peW);
  k_sacc<<<dim3((NN + 255) / 256, NCHUNK, BB), 256, 0, stream>>>(x, W, inv_norm, sPart);
  k_hid <<<dim3((NN + 255) / 256, BB), 256, 0, stream>>>(sPart, peW, hid4);
  k_den <<<BB * MM, 64, 0, stream>>>(hid4, invden);
  k_out <<<BB * CC / 4, 256, 0, stream>>>(x, hid4, inv_norm, invden, out);
}

// Round 2
// 149.800 us; speedup vs baseline: 1.1556x; 1.1556x over previous
//
#include <hip/hip_runtime.h>
#include <math.h>

#define BB 32
#define CC 2048
#define NN 784          // 28*28
#define NF4 196         // float4 per (b,c) row
#define MM 4
#define LAMBDA_ 1e-3f
#define EPS_ 1e-10f
#define LOG1E4 9.210340371976184f
#define NORM_BLOCKS (BB * CC / 4)   // 16384

__device__ __forceinline__ float wred(float v) {
#pragma unroll
  for (int off = 32; off > 0; off >>= 1) v += __shfl_down(v, off, 64);
  return v;
}

// ---- K1: fused  inv_norm[b*C+c] = 1/max(||x[b,c,:]||,eps)  +  peW[m,n] ----
__global__ __launch_bounds__(256) void k_norm_pew(const float* __restrict__ x,
                                                  const float* __restrict__ W,
                                                  float* __restrict__ inv_norm,
                                                  float* __restrict__ peW) {
  int bid  = blockIdx.x;
  int lane = threadIdx.x & 63;
  if (bid < NORM_BLOCKS) {
    int idx = bid * 4 + (threadIdx.x >> 6);        // (b*C+c)
    const float4* row = (const float4*)(x + (size_t)idx * NN);
    float ss = 0.f;
    for (int f = lane; f < NF4; f += 64) {
      float4 v = row[f];
      ss += v.x * v.x + v.y * v.y + v.z * v.z + v.w * v.w;
    }
    ss = wred(ss);
    if (lane == 0) inv_norm[idx] = 1.f / fmaxf(sqrtf(ss), EPS_);
  } else {
    int n = bid - NORM_BLOCKS;                     // 0..783
    int m = threadIdx.x >> 6;
    float acc = 0.f;
    for (int c = lane; c < CC; c += 64) {
      float di  = expf(-((float)(c & ~1) / (float)CC) * LOG1E4);
      float arg = (float)n * di;
      float pe  = (c & 1) ? cosf(arg) : sinf(arg);
      acc += pe * W[m * CC + c];
    }
    acc = wred(acc);
    if (lane == 0) peW[m * NN + n] = acc;
  }
}

// ---- K2: partial s over c-chunks, float4 over n (deterministic) ----
template <int NCH>
__global__ __launch_bounds__(256) void k_sacc(const float* __restrict__ x,
                                              const float* __restrict__ W,
                                              const float* __restrict__ inv_norm,
                                              float4* __restrict__ sPart4) {
  int t  = threadIdx.x;          // float4 index within row, t<196
  int ch = blockIdx.x;
  int b  = blockIdx.y;
  if (t >= NF4) return;
  const float4* xb  = (const float4*)(x + (size_t)b * CC * NN);
  const float* invb = inv_norm + b * CC;
  float4 a0 = {0,0,0,0}, a1 = {0,0,0,0}, a2 = {0,0,0,0}, a3 = {0,0,0,0};
  const int cper = CC / NCH;
  int c0 = ch * cper;
#pragma unroll 4
  for (int i = 0; i < cper; ++i) {
    int c = c0 + i;
    float4 xv = xb[(size_t)c * NF4 + t];
    float iw = invb[c];
    float w0 = iw * W[0 * CC + c];
    float w1 = iw * W[1 * CC + c];
    float w2 = iw * W[2 * CC + c];
    float w3 = iw * W[3 * CC + c];
    a0.x += xv.x * w0; a0.y += xv.y * w0; a0.z += xv.z * w0; a0.w += xv.w * w0;
    a1.x += xv.x * w1; a1.y += xv.y * w1; a1.z += xv.z * w1; a1.w += xv.w * w1;
    a2.x += xv.x * w2; a2.y += xv.y * w2; a2.z += xv.z * w2; a2.w += xv.w * w2;
    a3.x += xv.x * w3; a3.y += xv.y * w3; a3.z += xv.z * w3; a3.w += xv.w * w3;
  }
  size_t base = (((size_t)b * NCH + ch) * MM) * NF4 + t;
  sPart4[base + 0 * NF4] = a0;
  sPart4[base + 1 * NF4] = a1;
  sPart4[base + 2 * NF4] = a2;
  sPart4[base + 3 * NF4] = a3;
}

// ---- K3: hid4[(b*N+n)*4+m] = sigmoid(peW + sum_ch sPart) ----
template <int NCH>
__global__ __launch_bounds__(256) void k_hid(const float* __restrict__ sPart,
                                             const float* __restrict__ peW,
                                             float* __restrict__ hid4) {
  int n = blockIdx.x * 256 + threadIdx.x;
  int b = blockIdx.y;
  if (n >= NN) return;
  float h[MM];
#pragma unroll
  for (int m = 0; m < MM; ++m) {
    float s = peW[m * NN + n];
#pragma unroll
    for (int ch = 0; ch < NCH; ++ch)
      s += sPart[(((size_t)b * NCH + ch) * MM + m) * NN + n];
    h[m] = 1.f / (1.f + __expf(-s));
  }
  float4 hv = make_float4(h[0], h[1], h[2], h[3]);
  *(float4*)(hid4 + ((size_t)b * NN + n) * 4) = hv;
}

// ---- K4: out[b,c] = sum_m (inv*aX[m] + aP[m]) / (aD[m]+lambda), den fused ----
__global__ __launch_bounds__(256) void k_out(const float* __restrict__ x,
                                             const float* __restrict__ hid4,
                                             const float* __restrict__ inv_norm,
                                             float* __restrict__ out) {
  int idx  = blockIdx.x * 4 + (threadIdx.x >> 6);   // (b*C+c)
  int lane = threadIdx.x & 63;
  int b = idx >> 11;
  int c = idx & (CC - 1);
  const float4* row = (const float4*)(x + (size_t)idx * NN);
  const float4* hb  = (const float4*)(hid4 + (size_t)b * NN * 4);
  float di = __expf(-((float)(c & ~1) * (1.0f / CC)) * LOG1E4);
  bool use_sin = !(c & 1);
  float aX0=0,aX1=0,aX2=0,aX3=0, aP0=0,aP1=0,aP2=0,aP3=0, aD0=0,aD1=0,aD2=0,aD3=0;
  for (int f = lane; f < NF4; f += 64) {
    float4 xv = row[f];
    int n = f * 4;
    float4 h0 = hb[n + 0], h1 = hb[n + 1], h2 = hb[n + 2], h3 = hb[n + 3];
    float a0 = (float)(n + 0) * di, a1 = (float)(n + 1) * di;
    float a2 = (float)(n + 2) * di, a3 = (float)(n + 3) * di;
    float p0 = use_sin ? __sinf(a0) : __cosf(a0);
    float p1 = use_sin ? __sinf(a1) : __cosf(a1);
    float p2 = use_sin ? __sinf(a2) : __cosf(a2);
    float p3 = use_sin ? __sinf(a3) : __cosf(a3);
    aX0 += xv.x*h0.x + xv.y*h1.x + xv.z*h2.x + xv.w*h3.x;
    aX1 += xv.x*h0.y + xv.y*h1.y + xv.z*h2.y + xv.w*h3.y;
    aX2 += xv.x*h0.z + xv.y*h1.z + xv.z*h2.z + xv.w*h3.z;
    aX3 += xv.x*h0.w + xv.y*h1.w + xv.z*h2.w + xv.w*h3.w;
    aP0 += p0*h0.x + p1*h1.x + p2*h2.x + p3*h3.x;
    aP1 += p0*h0.y + p1*h1.y + p2*h2.y + p3*h3.y;
    aP2 += p0*h0.z + p1*h1.z + p2*h2.z + p3*h3.z;
    aP3 += p0*h0.w + p1*h1.w + p2*h2.w + p3*h3.w;
    aD0 += h0.x*h0.x + h1.x*h1.x + h2.x*h2.x + h3.x*h3.x;
    aD1 += h0.y*h0.y + h1.y*h1.y + h2.y*h2.y + h3.y*h3.y;
    aD2 += h0.z*h0.z + h1.z*h1.z + h2.z*h2.z + h3.z*h3.z;
    aD3 += h0.w*h0.w + h1.w*h1.w + h2.w*h2.w + h3.w*h3.w;
  }
  aX0 = wred(aX0); aX1 = wred(aX1); aX2 = wred(aX2); aX3 = wred(aX3);
  aP0 = wred(aP0); aP1 = wred(aP1); aP2 = wred(aP2); aP3 = wred(aP3);
  aD0 = wred(aD0); aD1 = wred(aD1); aD2 = wred(aD2); aD3 = wred(aD3);
  if (lane == 0) {
    float inv = inv_norm[idx];
    float r = (inv * aX0 + aP0) / (aD0 + LAMBDA_)
            + (inv * aX1 + aP1) / (aD1 + LAMBDA_)
            + (inv * aX2 + aP2) / (aD2 + LAMBDA_)
            + (inv * aX3 + aP3) / (aD3 + LAMBDA_);
    if (isnan(r)) r = 0.f;
    else if (isinf(r)) r = (r > 0.f) ? 3.4028234663852886e38f : -3.4028234663852886e38f;
    out[idx] = r;
  }
}

extern "C" void kernel_launch(void* const* d_in, const int* in_sizes, int n_in,
                              void* d_out, int out_size, void* d_ws, size_t ws_size,
                              hipStream_t stream) {
  const float* x = (const float*)d_in[0];   // (B, C, S, S)
  const float* W = (const float*)d_in[1];   // (M, C, 1)
  float* out = (float*)d_out;               // (B, 1, C)
  float* ws  = (float*)d_ws;

  float* inv_norm = ws;                                   // B*C   = 65536
  float* peW      = inv_norm + (size_t)BB * CC;           // M*N   = 3136
  float* hid4     = peW + (size_t)MM * NN;                // B*N*M = 401408
  float* sPart    = hid4 + (size_t)BB * NN * MM;          // B*NCH*M*N

  // ws budget check: 16 chunks (better occupancy) if workspace allows, else 8.
  const size_t base_floats = (size_t)BB * CC + MM * NN + (size_t)BB * NN * MM;
  const size_t need16 = (base_floats + (size_t)BB * 16 * MM * NN) * sizeof(float);

  k_norm_pew<<<NORM_BLOCKS + NN, 256, 0, stream>>>(x, W, inv_norm, peW);
  if (ws_size >= need16) {
    k_sacc<16><<<dim3(16, BB), 256, 0, stream>>>(x, W, inv_norm, (float4*)sPart);
    k_hid<16><<<dim3((NN + 255) / 256, BB), 256, 0, stream>>>(sPart, peW, hid4);
  } else {
    k_sacc<8><<<dim3(8, BB), 256, 0, stream>>>(x, W, inv_norm, (float4*)sPart);
    k_hid<8><<<dim3((NN + 255) / 256, BB), 256, 0, stream>>>(sPart, peW, hid4);
  }
  k_out<<<NORM_BLOCKS, 256, 0, stream>>>(x, hid4, inv_norm, out);
}